// Round 12
// baseline (175.876 us; speedup 1.0000x reference)
//
#include <hip/hip_runtime.h>

#define Bdim 32
#define Sdim 512
#define Hdim 1024
#define NEG 10
#define ROWS (Bdim * (Sdim - 1))   // 16352
#define WAVES_PER_BLOCK 8          // 512 threads, 8 rows per block
#define EMB_ELEMS (Bdim * Sdim * Hdim)   // 16,777,216
#define EMB_ROWS (Bdim * Sdim)           // 16,384

typedef float f32x2 __attribute__((ext_vector_type(2)));

// decode 4 packed fp8 (one dword) -> 4 floats via HW converter
static __device__ __forceinline__ void dec4(unsigned int w, float q[4]) {
    f32x2 lo = __builtin_amdgcn_cvt_pk_f32_fp8(w, false);
    f32x2 hi = __builtin_amdgcn_cvt_pk_f32_fp8(w, true);
    q[0] = lo.x; q[1] = lo.y; q[2] = hi.x; q[3] = hi.y;
}

// Pass 1: fp32 emb -> fp8 e4m3, PERMUTED row layout.
// Row layout: uint4 #l of a row packs elements {4*(l+64k)..+3} in word k.
// Then a coalesced uint4 read at lane l pairs exactly with coalesced
// float4 reads pred[lane + 64k]. Thread t <-> (row, l): 4 coalesced float4
// reads + 1 coalesced uint4 write.
__global__ __launch_bounds__(256) void emb_to_fp8_perm_kernel(
    const float* __restrict__ emb, uint4* __restrict__ out)
{
    const int t   = blockIdx.x * 256 + threadIdx.x;   // 0 .. EMB_ROWS*64-1
    const int row = t >> 6;
    const int l   = t & 63;
    const float4* src = (const float4*)emb + (size_t)row * (Hdim / 4);
    unsigned int w[4];
#pragma unroll
    for (int k = 0; k < 4; ++k) {
        float4 a = src[l + 64 * k];
        unsigned int x = 0;
        x = __builtin_amdgcn_cvt_pk_fp8_f32(a.x, a.y, x, false);
        x = __builtin_amdgcn_cvt_pk_fp8_f32(a.z, a.w, x, true);
        w[k] = x;
    }
    uint4 o; o.x = w[0]; o.y = w[1]; o.z = w[2]; o.w = w[3];
    out[t] = o;
}

// Pass 2: one wave per (b,s) row. All loads coalesced (16B/lane contiguous).
// Lane l's fp8 uint4 word k <-> pred float4 at [l + 64k] (same elements).
__global__ __launch_bounds__(512) void infonce_fp8_kernel(
    const float* __restrict__ enc,
    const uint4* __restrict__ emb8,   // permuted fp8 copy, 64 uint4 per row
    const int*   __restrict__ negidx,
    const float* __restrict__ temp,
    float* __restrict__ out)
{
    const int tid  = threadIdx.x;
    const int wave = tid >> 6;
    const int lane = tid & 63;
    const int row  = blockIdx.x * WAVES_PER_BLOCK + wave;
    const int b    = row / (Sdim - 1);
    const int s    = row % (Sdim - 1);

    const float4* pred = (const float4*)(enc + (size_t)(b * Sdim + s) * Hdim);
    const uint4*  posq = emb8 + (size_t)(b * Sdim + s + 1) * 64 + lane;

    const int* ni = negidx + (size_t)row * NEG;
    int idx[NEG];
#pragma unroll
    for (int n = 0; n < NEG; ++n) {
        int v = ni[n];
        idx[n] = v + ((v >= b * Sdim) ? Sdim : 0);
    }

    float4 p[4];
#pragma unroll
    for (int k = 0; k < 4; ++k) p[k] = pred[lane + 64 * k];

    float acc[13];
#pragma unroll
    for (int k = 0; k < 13; ++k) acc[k] = 0.0f;

    // positive: dot, |p|^2, |q|^2
    {
        uint4 g = *posq;
        unsigned int w[4] = {g.x, g.y, g.z, g.w};
#pragma unroll
        for (int k = 0; k < 4; ++k) {
            float q[4]; dec4(w[k], q);
            acc[0] += p[k].x * q[0] + p[k].y * q[1] + p[k].z * q[2] + p[k].w * q[3];
            acc[1] += p[k].x * p[k].x + p[k].y * p[k].y + p[k].z * p[k].z + p[k].w * p[k].w;
            acc[2] += q[0] * q[0] + q[1] * q[1] + q[2] * q[2] + q[3] * q[3];
        }
    }

#pragma unroll
    for (int n = 0; n < NEG; ++n) {
        uint4 g = *(emb8 + (size_t)idx[n] * 64 + lane);
        unsigned int w[4] = {g.x, g.y, g.z, g.w};
        float d = 0.0f;
#pragma unroll
        for (int k = 0; k < 4; ++k) {
            float q[4]; dec4(w[k], q);
            d += p[k].x * q[0] + p[k].y * q[1] + p[k].z * q[2] + p[k].w * q[3];
        }
        acc[3 + n] = d;
    }

#pragma unroll
    for (int k = 0; k < 13; ++k) {
        float v = acc[k];
#pragma unroll
        for (int off = 1; off < 64; off <<= 1)
            v += __shfl_xor(v, off, 64);
        acc[k] = v;
    }

    __shared__ float wloss[WAVES_PER_BLOCK];
    if (lane == 0) {
        const float invt = 1.0f / *temp;
        const float pn = fmaxf(sqrtf(acc[1]), 1e-8f);
        const float qn = fmaxf(sqrtf(acc[2]), 1e-8f);
        const float pos_score = acc[0] / (pn * qn) * invt;

        float m = pos_score;
        float negs[NEG];
#pragma unroll
        for (int n = 0; n < NEG; ++n) {
            negs[n] = acc[3 + n] * invt;
            m = fmaxf(m, negs[n]);
        }
        float sum = expf(pos_score - m);
#pragma unroll
        for (int n = 0; n < NEG; ++n) sum += expf(negs[n] - m);
        const float lse = m + logf(sum);

        wloss[wave] = (lse - pos_score) * (1.0f / (float)ROWS);
    }
    __syncthreads();

    if (tid == 0) {
        float sum = 0.0f;
#pragma unroll
        for (int w = 0; w < WAVES_PER_BLOCK; ++w) sum += wloss[w];
        atomicAdd(out, sum);
    }
}

// fp32 fallback (ws too small) — round-4 kernel.
__global__ __launch_bounds__(512) void infonce_wave_kernel(
    const float* __restrict__ enc, const float* __restrict__ emb,
    const int* __restrict__ negidx, const float* __restrict__ temp,
    float* __restrict__ out)
{
    const int tid  = threadIdx.x;
    const int wave = tid >> 6;
    const int lane = tid & 63;
    const int row  = blockIdx.x * WAVES_PER_BLOCK + wave;
    const int b    = row / (Sdim - 1);
    const int s    = row % (Sdim - 1);

    const float4* pred = (const float4*)(enc + (size_t)(b * Sdim + s) * Hdim);
    const float4* pos  = (const float4*)(emb + (size_t)(b * Sdim + s + 1) * Hdim);

    const int* ni = negidx + (size_t)row * NEG;
    int idx[NEG];
#pragma unroll
    for (int n = 0; n < NEG; ++n) {
        int v = ni[n];
        idx[n] = v + ((v >= b * Sdim) ? Sdim : 0);
    }

    float4 p[4], q[4];
#pragma unroll
    for (int j = 0; j < 4; ++j) p[j] = pred[lane + 64 * j];
#pragma unroll
    for (int j = 0; j < 4; ++j) q[j] = pos[lane + 64 * j];

    float acc[13];
#pragma unroll
    for (int k = 0; k < 13; ++k) acc[k] = 0.0f;
#pragma unroll
    for (int j = 0; j < 4; ++j) {
        acc[0] += p[j].x * q[j].x + p[j].y * q[j].y + p[j].z * q[j].z + p[j].w * q[j].w;
        acc[1] += p[j].x * p[j].x + p[j].y * p[j].y + p[j].z * p[j].z + p[j].w * p[j].w;
        acc[2] += q[j].x * q[j].x + q[j].y * q[j].y + q[j].z * q[j].z + q[j].w * q[j].w;
    }
#pragma unroll
    for (int n = 0; n < NEG; ++n) {
        const float4* neg = (const float4*)(emb + (size_t)idx[n] * Hdim);
        float d = 0.0f;
#pragma unroll
        for (int j = 0; j < 4; ++j) {
            float4 v = neg[lane + 64 * j];
            d += p[j].x * v.x + p[j].y * v.y + p[j].z * v.z + p[j].w * v.w;
        }
        acc[3 + n] = d;
    }
#pragma unroll
    for (int k = 0; k < 13; ++k) {
        float v = acc[k];
#pragma unroll
        for (int off = 1; off < 64; off <<= 1)
            v += __shfl_xor(v, off, 64);
        acc[k] = v;
    }
    __shared__ float wloss[WAVES_PER_BLOCK];
    if (lane == 0) {
        const float invt = 1.0f / *temp;
        const float pn = fmaxf(sqrtf(acc[1]), 1e-8f);
        const float qn = fmaxf(sqrtf(acc[2]), 1e-8f);
        const float pos_score = acc[0] / (pn * qn) * invt;
        float m = pos_score;
        float negs[NEG];
#pragma unroll
        for (int n = 0; n < NEG; ++n) {
            negs[n] = acc[3 + n] * invt;
            m = fmaxf(m, negs[n]);
        }
        float sum = expf(pos_score - m);
#pragma unroll
        for (int n = 0; n < NEG; ++n) sum += expf(negs[n] - m);
        wloss[wave] = (m + logf(sum) - pos_score) * (1.0f / (float)ROWS);
    }
    __syncthreads();
    if (tid == 0) {
        float sum = 0.0f;
#pragma unroll
        for (int w = 0; w < WAVES_PER_BLOCK; ++w) sum += wloss[w];
        atomicAdd(out, sum);
    }
}

extern "C" void kernel_launch(void* const* d_in, const int* in_sizes, int n_in,
                              void* d_out, int out_size, void* d_ws, size_t ws_size,
                              hipStream_t stream) {
    const float* enc    = (const float*)d_in[0];
    const float* emb    = (const float*)d_in[1];
    const int*   negidx = (const int*)d_in[2];
    const float* temp   = (const float*)d_in[3];
    float* out = (float*)d_out;

    hipMemsetAsync(out, 0, sizeof(float) * out_size, stream);

    if (ws_size >= (size_t)EMB_ELEMS) {
        uint4* emb8 = (uint4*)d_ws;
        emb_to_fp8_perm_kernel<<<EMB_ROWS * 64 / 256, 256, 0, stream>>>(emb, emb8);
        infonce_fp8_kernel<<<ROWS / WAVES_PER_BLOCK, 512, 0, stream>>>(
            enc, emb8, negidx, temp, out);
    } else {
        infonce_wave_kernel<<<ROWS / WAVES_PER_BLOCK, 512, 0, stream>>>(
            enc, emb, negidx, temp, out);
    }
}